// Round 3
// baseline (324.991 us; speedup 1.0000x reference)
//
#include <hip/hip_runtime.h>
#include <hip/hip_bf16.h>

// Problem constants (from reference setup_inputs)
#define BB 8
#define MM 100
#define NN 32
#define HWSZ 65536           // 256*256
#define IOU_THR 0.5f
#define SCORE_THR 0.0f

// Output layout (concatenated flat, element offsets; dtype = f32 or bf16,
// detected at runtime):
//   gt_masks : BB*NN*HWSZ = 16,777,216
//   flags    : BB*NN      = 256
//   gtm      : BB*NN      = 256
//   biou     : BB*NN      = 256
#define MASKS_ELEMS ((size_t)BB * NN * HWSZ)

// d_ws layout (ints): [0..255] = gtm scratch, [256] = dtype flag (1 = bf16)
#define WS_FLAG 256

// Round f32 -> bf16 (RNE) -> f32 (emulates one bf16 op exactly).
__device__ __forceinline__ float bf16r(float x) {
    unsigned u = __float_as_uint(x);
    u = (u + 0x7FFFu + ((u >> 16) & 1u)) & 0xFFFF0000u;
    return __uint_as_float(u);
}

// ---------------------------------------------------------------------------
// Kernel 0: dtype sniff. Reads first 2048 B of gt_boxes (1024 elements; safe
// for both f32 [4096 B buffer] and bf16 [2048 B buffer] interpretations).
// If data is bf16 pairs, the LOW 16 bits of each u32 are a plausible box
// coordinate (sign 0, bf16 exponent in [118,137]) ~100% of the time; if f32,
// they are uniform mantissa bits (~4% pass). 1 wave, 512 samples.
// ---------------------------------------------------------------------------
__global__ void sniff_kernel(const unsigned* __restrict__ gt_raw,
                             int* __restrict__ ws) {
    const int t = threadIdx.x;   // 64 threads = 1 wave
    int cnt = 0;
    #pragma unroll
    for (int k = 0; k < 8; ++k) {
        const unsigned u  = gt_raw[t * 8 + k];
        const unsigned lo = u & 0xFFFFu;
        const unsigned ex = (lo >> 7) & 0xFFu;
        if (((lo >> 15) == 0u) && ex >= 118u && ex <= 137u) ++cnt;
    }
    #pragma unroll
    for (int m = 1; m < 64; m <<= 1) cnt += __shfl_xor(cnt, m, 64);
    if (t == 0) ws[WS_FLAG] = (cnt >= 256) ? 1 : 0;
}

// ---------------------------------------------------------------------------
// Kernel 1: per-batch IoU + stable-sorted greedy matching. One block/batch.
// Dual-dtype: f32 path = plain f32 math (bit-exact vs f32 numpy reference);
// bf16 path = per-op bf16 RNE rounding.
// ---------------------------------------------------------------------------
__global__ __launch_bounds__(256) void match_kernel(
    const void* __restrict__ pred_boxes,  // [BB,MM,4]
    const void* __restrict__ gt_boxes,    // [BB,NN,4]
    const void* __restrict__ pred_scores, // [BB,MM]
    const void* __restrict__ mask_score,  // [BB,MM]
    void* __restrict__ out,
    int* __restrict__ ws)
{
    const int b = blockIdx.x;
    const int t = threadIdx.x;
    const bool isbf = (ws[WS_FLAG] != 0);

    __shared__ float pb[MM][4];
    __shared__ float gb[NN][4];
    __shared__ float sc[MM];
    __shared__ float area2[NN];
    __shared__ float iou_s[MM][NN];   // lane j -> bank j, conflict-free
    __shared__ int   order_s[MM];

    const __hip_bfloat16* pb_h = (const __hip_bfloat16*)pred_boxes;
    const float*          pb_f = (const float*)pred_boxes;
    const __hip_bfloat16* gb_h = (const __hip_bfloat16*)gt_boxes;
    const float*          gb_f = (const float*)gt_boxes;
    const __hip_bfloat16* sc_h = (const __hip_bfloat16*)pred_scores;
    const float*          sc_f = (const float*)pred_scores;

    for (int i = t; i < MM * 4; i += 256) {
        const size_t o = (size_t)b * MM * 4 + i;
        pb[i >> 2][i & 3] = isbf ? __bfloat162float(pb_h[o]) : pb_f[o];
    }
    for (int i = t; i < NN * 4; i += 256) {
        const size_t o = (size_t)b * NN * 4 + i;
        gb[i >> 2][i & 3] = isbf ? __bfloat162float(gb_h[o]) : gb_f[o];
    }
    for (int i = t; i < MM; i += 256) {
        const size_t o = (size_t)b * MM + i;
        sc[i] = isbf ? __bfloat162float(sc_h[o]) : sc_f[o];
    }
    __syncthreads();

    // rnd(): per-op rounding in bf16 mode, identity in f32 mode.
    auto rnd = [&](float x) { return isbf ? bf16r(x) : x; };

    if (t < NN)
        area2[t] = rnd(rnd(gb[t][2] - gb[t][0]) * rnd(gb[t][3] - gb[t][1]));
    __syncthreads();

    // IoU matrix — reference op order: inter / ((a1 + a2) - inter)
    for (int e = t; e < MM * NN; e += 256) {
        const int i = e >> 5;          // / NN
        const int j = e & 31;          // % NN
        const float a1 = rnd(rnd(pb[i][2] - pb[i][0]) * rnd(pb[i][3] - pb[i][1]));
        const float lx = fmaxf(pb[i][0], gb[j][0]);
        const float ly = fmaxf(pb[i][1], gb[j][1]);
        const float rx = fminf(pb[i][2], gb[j][2]);
        const float ry = fminf(pb[i][3], gb[j][3]);
        const float w  = fmaxf(rnd(rx - lx), 0.0f);
        const float h  = fmaxf(rnd(ry - ly), 0.0f);
        const float inter = rnd(w * h);
        const float denom = rnd(rnd(a1 + area2[j]) - inter);
        iou_s[i][j] = rnd(inter / denom);
    }

    // Stable descending argsort: rank_i = #{j : s_j > s_i or (s_j==s_i && j<i)}
    if (t < MM) {
        const float si = sc[t];
        int r = 0;
        for (int j = 0; j < MM; ++j) {
            const float sj = sc[j];
            if (sj > si || (sj == si && j < t)) ++r;
        }
        order_s[r] = t;
    }
    __syncthreads();

    // Greedy matching: lanes 0..31, lane j owns gt j.
    if (t < 32) {
        const int j = t;
        int   gtm_j  = -1;
        float biou_j = 0.0f;

        for (int s = 0; s < MM; ++s) {
            const int i = order_s[s];
            const float row = iou_s[i][j];
            // faithful: gt available iff gtm[j] <= 0 (NOT > -1)
            const float cand = (gtm_j <= 0 && row >= IOU_THR) ? row : -1.0f;

            // 32-lane argmax, first-max (lowest j) tie-break == jnp.argmax
            float v  = cand;
            int   vj = j;
            #pragma unroll
            for (int m = 1; m < 32; m <<= 1) {
                const float ov = __shfl_xor(v, m, 32);
                const int   oj = __shfl_xor(vj, m, 32);
                if (ov > v || (ov == v && oj < vj)) { v = ov; vj = oj; }
            }
            const bool doit = (sc[i] >= SCORE_THR) && (v >= IOU_THR);
            if (doit && vj == j) { gtm_j = i; biou_j = v; }
        }

        const int bn = b * NN + j;
        const bool matched = (gtm_j > -1);
        float fs = 0.0f;
        if (matched) {
            const size_t o = (size_t)b * MM + gtm_j;
            fs = isbf ? __bfloat162float(((const __hip_bfloat16*)mask_score)[o])
                      : ((const float*)mask_score)[o];
        }
        if (isbf) {
            __hip_bfloat16* o = (__hip_bfloat16*)out;
            o[MASKS_ELEMS + bn]       = __float2bfloat16(fs);
            o[MASKS_ELEMS + 256 + bn] = __float2bfloat16((float)gtm_j);
            o[MASKS_ELEMS + 512 + bn] = __float2bfloat16(biou_j);
        } else {
            float* o = (float*)out;
            o[MASKS_ELEMS + bn]       = fs;
            o[MASKS_ELEMS + 256 + bn] = (float)gtm_j;
            o[MASKS_ELEMS + 512 + bn] = biou_j;
        }
        ws[bn] = gtm_j;
    }
}

// ---------------------------------------------------------------------------
// Kernel 2: mask gather/zero, byte-addressed so it works for both dtypes.
// 64 chunks of 4 KiB per (b,n) mask (f32 mask = 256 KiB); bf16 mode uses
// only the first 32 chunks (mask = 128 KiB). 256 thr x 16 B each.
// ---------------------------------------------------------------------------
__global__ __launch_bounds__(256) void gather_kernel(
    const void* __restrict__ pred_masks,
    const int* __restrict__ ws,
    void* __restrict__ out)
{
    const bool isbf = (ws[WS_FLAG] != 0);
    const int bn    = blockIdx.x >> 6;   // 64 chunks per mask
    const int chunk = blockIdx.x & 63;
    const size_t mbytes = isbf ? (size_t)HWSZ * 2 : (size_t)HWSZ * 4;

    const size_t off = (size_t)chunk * 4096 + (size_t)threadIdx.x * 16;
    if (off >= mbytes) return;           // block-uniform in bf16 mode

    const int idx = ws[bn];
    const int b   = bn >> 5;             // NN = 32

    uint4 v = make_uint4(0u, 0u, 0u, 0u);
    if (idx > -1) {
        v = *(const uint4*)((const char*)pred_masks +
                            ((size_t)b * MM + idx) * mbytes + off);
    }
    *(uint4*)((char*)out + (size_t)bn * mbytes + off) = v;
}

extern "C" void kernel_launch(void* const* d_in, const int* in_sizes, int n_in,
                              void* d_out, int out_size, void* d_ws, size_t ws_size,
                              hipStream_t stream) {
    const void* pred_boxes  = d_in[0];
    const void* gt_boxes    = d_in[1];
    const void* pred_scores = d_in[2];
    const void* pred_masks  = d_in[3];
    const void* mask_score  = d_in[4];
    int* ws = (int*)d_ws;

    sniff_kernel<<<1, 64, 0, stream>>>((const unsigned*)gt_boxes, ws);
    match_kernel<<<BB, 256, 0, stream>>>(pred_boxes, gt_boxes, pred_scores,
                                         mask_score, d_out, ws);
    gather_kernel<<<BB * NN * 64, 256, 0, stream>>>(pred_masks, ws, d_out);
}

// Round 4
// 322.630 us; speedup vs baseline: 1.0073x; 1.0073x over previous
//
#include <hip/hip_runtime.h>
#include <hip/hip_bf16.h>

// Problem constants (from reference setup_inputs)
#define BB 8
#define MM 100
#define NN 32
#define HWSZ 65536           // 256*256
#define IOU_THR 0.5f
#define SCORE_THR 0.0f

// Output layout (concatenated flat, element offsets; dtype f32 or bf16,
// runtime-detected — R3 bench confirmed the f32 path is the live one):
//   gt_masks : BB*NN*HWSZ = 16,777,216
//   flags    : BB*NN      = 256
//   gtm      : BB*NN      = 256
//   biou     : BB*NN      = 256
#define MASKS_ELEMS ((size_t)BB * NN * HWSZ)

// d_ws layout (ints): [0..255] = gtm scratch, [256] = dtype flag (1 = bf16)
#define WS_FLAG 256

// Round f32 -> bf16 (RNE) -> f32 (emulates one bf16 op exactly).
__device__ __forceinline__ float bf16r(float x) {
    unsigned u = __float_as_uint(x);
    u = (u + 0x7FFFu + ((u >> 16) & 1u)) & 0xFFFF0000u;
    return __uint_as_float(u);
}

// ---------------------------------------------------------------------------
// Kernel 1: dtype sniff (inlined, wave 0) + per-batch IoU + stable-sorted
// greedy matching. One block per batch image; every block re-derives the
// dtype flag locally (2 KiB read, deterministic), block 0 publishes it for
// the gather kernel.
// ---------------------------------------------------------------------------
__global__ __launch_bounds__(256) void match_kernel(
    const void* __restrict__ pred_boxes,  // [BB,MM,4]
    const void* __restrict__ gt_boxes,    // [BB,NN,4]
    const void* __restrict__ pred_scores, // [BB,MM]
    const void* __restrict__ mask_score,  // [BB,MM]
    void* __restrict__ out,
    int* __restrict__ ws)
{
    const int b = blockIdx.x;
    const int t = threadIdx.x;

    __shared__ float pb[MM][4];
    __shared__ float gb[NN][4];
    __shared__ float sc[MM];
    __shared__ float area2[NN];
    __shared__ float iou_s[MM][NN];   // lane j -> bank j, conflict-free
    __shared__ int   order_s[MM];
    __shared__ int   flag_s;

    // --- dtype sniff (wave 0): first 2048 B of gt_boxes as 512 u32. If bf16
    // pairs, low 16 bits of each u32 are a plausible coordinate (sign 0,
    // exponent 118..137) ~100%; if f32, uniform mantissa bits (~4%).
    if (t < 64) {
        const unsigned* gt_raw = (const unsigned*)gt_boxes;
        int cnt = 0;
        #pragma unroll
        for (int k = 0; k < 8; ++k) {
            const unsigned u  = gt_raw[t * 8 + k];
            const unsigned lo = u & 0xFFFFu;
            const unsigned ex = (lo >> 7) & 0xFFu;
            if (((lo >> 15) == 0u) && ex >= 118u && ex <= 137u) ++cnt;
        }
        #pragma unroll
        for (int m = 1; m < 64; m <<= 1) cnt += __shfl_xor(cnt, m, 64);
        if (t == 0) {
            flag_s = (cnt >= 256) ? 1 : 0;
            if (b == 0) ws[WS_FLAG] = flag_s;   // publish for gather_kernel
        }
    }
    __syncthreads();
    const bool isbf = (flag_s != 0);

    const __hip_bfloat16* pb_h = (const __hip_bfloat16*)pred_boxes;
    const float*          pb_f = (const float*)pred_boxes;
    const __hip_bfloat16* gb_h = (const __hip_bfloat16*)gt_boxes;
    const float*          gb_f = (const float*)gt_boxes;
    const __hip_bfloat16* sc_h = (const __hip_bfloat16*)pred_scores;
    const float*          sc_f = (const float*)pred_scores;

    for (int i = t; i < MM * 4; i += 256) {
        const size_t o = (size_t)b * MM * 4 + i;
        pb[i >> 2][i & 3] = isbf ? __bfloat162float(pb_h[o]) : pb_f[o];
    }
    for (int i = t; i < NN * 4; i += 256) {
        const size_t o = (size_t)b * NN * 4 + i;
        gb[i >> 2][i & 3] = isbf ? __bfloat162float(gb_h[o]) : gb_f[o];
    }
    for (int i = t; i < MM; i += 256) {
        const size_t o = (size_t)b * MM + i;
        sc[i] = isbf ? __bfloat162float(sc_h[o]) : sc_f[o];
    }
    __syncthreads();

    // rnd(): per-op bf16 rounding in bf16 mode, identity in f32 mode.
    auto rnd = [&](float x) { return isbf ? bf16r(x) : x; };

    if (t < NN)
        area2[t] = rnd(rnd(gb[t][2] - gb[t][0]) * rnd(gb[t][3] - gb[t][1]));
    __syncthreads();

    // IoU matrix — reference op order: inter / ((a1 + a2) - inter)
    for (int e = t; e < MM * NN; e += 256) {
        const int i = e >> 5;          // / NN
        const int j = e & 31;          // % NN
        const float a1 = rnd(rnd(pb[i][2] - pb[i][0]) * rnd(pb[i][3] - pb[i][1]));
        const float lx = fmaxf(pb[i][0], gb[j][0]);
        const float ly = fmaxf(pb[i][1], gb[j][1]);
        const float rx = fminf(pb[i][2], gb[j][2]);
        const float ry = fminf(pb[i][3], gb[j][3]);
        const float w  = fmaxf(rnd(rx - lx), 0.0f);
        const float h  = fmaxf(rnd(ry - ly), 0.0f);
        const float inter = rnd(w * h);
        const float denom = rnd(rnd(a1 + area2[j]) - inter);
        iou_s[i][j] = rnd(inter / denom);
    }

    // Stable descending argsort: rank_i = #{j : s_j > s_i or (s_j==s_i && j<i)}
    // Matches jnp.argsort(-scores) (stable) exactly, including ties.
    if (t < MM) {
        const float si = sc[t];
        int r = 0;
        for (int j = 0; j < MM; ++j) {
            const float sj = sc[j];
            if (sj > si || (sj == si && j < t)) ++r;
        }
        order_s[r] = t;
    }
    __syncthreads();

    // Greedy matching: lanes 0..31, lane j owns gt j.
    if (t < 32) {
        const int j = t;
        int   gtm_j  = -1;
        float biou_j = 0.0f;

        for (int s = 0; s < MM; ++s) {
            const int i = order_s[s];
            const float row = iou_s[i][j];
            // faithful: gt available iff gtm[j] <= 0 (NOT > -1)
            const float cand = (gtm_j <= 0 && row >= IOU_THR) ? row : -1.0f;

            // 32-lane argmax, first-max (lowest j) tie-break == jnp.argmax
            float v  = cand;
            int   vj = j;
            #pragma unroll
            for (int m = 1; m < 32; m <<= 1) {
                const float ov = __shfl_xor(v, m, 32);
                const int   oj = __shfl_xor(vj, m, 32);
                if (ov > v || (ov == v && oj < vj)) { v = ov; vj = oj; }
            }
            const bool doit = (sc[i] >= SCORE_THR) && (v >= IOU_THR);
            if (doit && vj == j) { gtm_j = i; biou_j = v; }
        }

        const int bn = b * NN + j;
        const bool matched = (gtm_j > -1);
        float fs = 0.0f;
        if (matched) {
            const size_t o = (size_t)b * MM + gtm_j;
            fs = isbf ? __bfloat162float(((const __hip_bfloat16*)mask_score)[o])
                      : ((const float*)mask_score)[o];
        }
        if (isbf) {
            __hip_bfloat16* o = (__hip_bfloat16*)out;
            o[MASKS_ELEMS + bn]       = __float2bfloat16(fs);
            o[MASKS_ELEMS + 256 + bn] = __float2bfloat16((float)gtm_j);
            o[MASKS_ELEMS + 512 + bn] = __float2bfloat16(biou_j);
        } else {
            float* o = (float*)out;
            o[MASKS_ELEMS + bn]       = fs;
            o[MASKS_ELEMS + 256 + bn] = (float)gtm_j;
            o[MASKS_ELEMS + 512 + bn] = biou_j;
        }
        ws[bn] = gtm_j;
    }
}

// ---------------------------------------------------------------------------
// Kernel 2: mask gather/zero, byte-addressed for both dtypes. 32 chunks of
// 8 KiB per (b,n) mask (f32 mask = 256 KiB; bf16 uses chunks 0..15).
// 256 thr x 2 uint4 = 32 B/thread. Branches are block-uniform.
// ---------------------------------------------------------------------------
__global__ __launch_bounds__(256) void gather_kernel(
    const void* __restrict__ pred_masks,
    const int* __restrict__ ws,
    void* __restrict__ out)
{
    const bool isbf = (ws[WS_FLAG] != 0);
    const int bn    = blockIdx.x >> 5;   // 32 chunks per mask
    const int chunk = blockIdx.x & 31;
    const size_t mbytes = isbf ? (size_t)HWSZ * 2 : (size_t)HWSZ * 4;

    const size_t base = (size_t)chunk * 8192 + (size_t)threadIdx.x * 16;
    if (base >= mbytes) return;          // bf16 mode: upper chunks idle

    const int idx = ws[bn];
    const int b   = bn >> 5;             // NN = 32

    uint4 v0 = make_uint4(0u, 0u, 0u, 0u);
    uint4 v1 = make_uint4(0u, 0u, 0u, 0u);
    if (idx > -1) {
        const char* src = (const char*)pred_masks + ((size_t)b * MM + idx) * mbytes;
        v0 = *(const uint4*)(src + base);
        v1 = *(const uint4*)(src + base + 4096);
    }
    char* dst = (char*)out + (size_t)bn * mbytes;
    *(uint4*)(dst + base)        = v0;
    *(uint4*)(dst + base + 4096) = v1;
}

extern "C" void kernel_launch(void* const* d_in, const int* in_sizes, int n_in,
                              void* d_out, int out_size, void* d_ws, size_t ws_size,
                              hipStream_t stream) {
    const void* pred_boxes  = d_in[0];
    const void* gt_boxes    = d_in[1];
    const void* pred_scores = d_in[2];
    const void* pred_masks  = d_in[3];
    const void* mask_score  = d_in[4];
    int* ws = (int*)d_ws;

    match_kernel<<<BB, 256, 0, stream>>>(pred_boxes, gt_boxes, pred_scores,
                                         mask_score, d_out, ws);
    gather_kernel<<<BB * NN * 32, 256, 0, stream>>>(pred_masks, ws, d_out);
}